// Round 7
// baseline (144.887 us; speedup 1.0000x reference)
//
#include <hip/hip_runtime.h>

// out[b,f,t] = sum_{c,dt} exp(-g*x[b,c,t+dt])[x!=0] * w[c*48+dt*16+f]
// im2col GEMM, M=t (98/batch), N=f (16), K=(c,dt). MFMA bf16 16x16x32.
// E LDS layout: [c/8][t][c&7] ushort (16B t-rows, 2048B group stride),
// XOR-swizzled (byte bits 5-6 ^= (t>>2)&3) so coalesced staging writes
// spread banks while A-fragments stay one ds_read_b128.
#define BB     64
#define NNCH   10000
#define TOUT   98
#define FF     16
#define CPB    64            // channels per chunk
#define NCHUNK 157           // ceil(10000/64)
#define CH     4             // chunks per block (acc persists across chunks)
#define NCO    40            // ceil(NCHUNK/CH)
#define EROWS  128           // padded t rows (t<=113 used, >=100 zero)
#define WP     200           // W row pitch (ushort)

typedef __attribute__((ext_vector_type(8))) short s8v;   // 8 bf16
typedef __attribute__((ext_vector_type(4))) float f4v;   // 4 fp32 acc

__device__ __forceinline__ ushort bf_rne(float v) {
    unsigned b = __float_as_uint(v);
    return (ushort)((b + 0x7FFFu + ((b >> 16) & 1u)) >> 16);
}

__device__ __forceinline__ int eaddr(int c, int t) {
    int byte = ((c >> 3) << 11) | (t << 4) | ((c & 7) << 1);
    return byte ^ (((t >> 2) & 3) << 5);   // swizzle keeps 16B chunks intact
}

__global__ __launch_bounds__(256) void tgcnn_mfma(
    const float* __restrict__ x,      // (B, NN, T=100) fp32
    const float* __restrict__ w,      // (NN*3, 16) fp32: c*48 + dt*16 + f
    const float* __restrict__ gammat, // fp32 scalar
    float* __restrict__ out)          // (B, F, 1, TOUT) fp32, pre-zeroed
{
    __shared__ __align__(16) ushort E8[8 * EROWS * 8];   // 16384 B
    __shared__ __align__(16) ushort W[FF][WP];           // 6400 B

    const int tid = threadIdx.x;
    const int bid = blockIdx.x;
    const int b   = bid / NCO;
    const int co  = bid - b * NCO;

    const float gt    = gammat[0];
    const float gamma = 10.0f / (1.0f + __expf(-gt));
    const float kk    = -gamma * 1.4426950408889634f;   // exp(-g*x)=exp2(kk*x)

    // zero E once: pad rows (t>=100) must stay zero; t<100 rewritten per chunk
    {
        uint4* e4 = (uint4*)E8;
        #pragma unroll
        for (int i = tid; i < 1024; i += 256) e4[i] = make_uint4(0, 0, 0, 0);
    }
    __syncthreads();

    const int wave  = tid >> 6, lane = tid & 63;
    const int tcol  = lane & 15;     // A row (t in tile) / B,D col (f)
    const int kb    = lane >> 4;     // k-octet
    const int tile0 = wave, tile1 = wave + 4;

    f4v acc0 = {0.f, 0.f, 0.f, 0.f};
    f4v acc1 = {0.f, 0.f, 0.f, 0.f};

    const float4* x4  = (const float4*)x;
    const float4* wg4 = (const float4*)w;
    char* eb = (char*)E8;

    for (int kc = 0; kc < CH; ++kc) {
        const int cs = co * CH + kc;
        if (cs >= NCHUNK) break;
        const int cbase = cs * CPB;

        // stage E: coalesced (thread i -> cl=i/25, q=i%25; 1600 float4 = 25.6KB
        // contiguous), exp-transform, 4 swizzled ds_write_b16 per float4
        for (int r = 0; r < 7; ++r) {
            const int i = r * 256 + tid;
            if (i < 1600) {
                const int cl = i / 25, q = i - cl * 25;
                const int c  = cbase + cl;
                float4 v = make_float4(0.f, 0.f, 0.f, 0.f);
                if (c < NNCH) v = x4[((size_t)b * NNCH + c) * 25 + q];
                const int t0 = q * 4;
                ushort e0 = (v.x != 0.f) ? bf_rne(exp2f(kk * v.x)) : 0;
                ushort e1 = (v.y != 0.f) ? bf_rne(exp2f(kk * v.y)) : 0;
                ushort e2 = (v.z != 0.f) ? bf_rne(exp2f(kk * v.z)) : 0;
                ushort e3 = (v.w != 0.f) ? bf_rne(exp2f(kk * v.w)) : 0;
                *(ushort*)(eb + eaddr(cl, t0 + 0)) = e0;
                *(ushort*)(eb + eaddr(cl, t0 + 1)) = e1;
                *(ushort*)(eb + eaddr(cl, t0 + 2)) = e2;
                *(ushort*)(eb + eaddr(cl, t0 + 3)) = e3;
            }
        }

        // stage W: w[c*48+dt*16+f] -> W[f][dt*64+cl] (zero-fill tail channels)
        for (int i = tid; i < 768; i += 256) {
            const int wc = i / 12, r = i - wc * 12;
            const int c  = cbase + wc;
            float4 wv = make_float4(0.f, 0.f, 0.f, 0.f);
            if (c < NNCH) wv = wg4[(size_t)c * 12 + r];
            const int dt = r >> 2, fq = (r & 3) * 4, kp = dt * CPB + wc;
            W[fq + 0][kp] = bf_rne(wv.x);
            W[fq + 1][kp] = bf_rne(wv.y);
            W[fq + 2][kp] = bf_rne(wv.z);
            W[fq + 3][kp] = bf_rne(wv.w);
        }
        __syncthreads();

        // MFMA: 7 t-tiles; wave owns {wave, wave+4}; A = one b128 per MFMA
        #pragma unroll
        for (int ks = 0; ks < 6; ++ks) {
            const int dt = ks >> 1;
            const int cb = (ks & 1) * 32 + kb * 8;
            s8v bfrag = *(const s8v*)&W[tcol][ks * 32 + kb * 8];
            {
                const int trow = tile0 * 16 + tcol + dt;
                s8v a0 = *(const s8v*)(eb + eaddr(cb, trow));
                acc0 = __builtin_amdgcn_mfma_f32_16x16x32_bf16(a0, bfrag, acc0, 0, 0, 0);
            }
            if (tile1 < 7) {
                const int trow = tile1 * 16 + tcol + dt;
                s8v a1 = *(const s8v*)(eb + eaddr(cb, trow));
                acc1 = __builtin_amdgcn_mfma_f32_16x16x32_bf16(a1, bfrag, acc1, 0, 0, 0);
            }
        }
        __syncthreads();
    }

    // epilogue: atomics straight into out (B,F,1,T); D: col=lane&15=f,
    // row=(lane>>4)*4+r = t within tile
    float* ob = out + (size_t)b * FF * TOUT;
    const int f = lane & 15;
    const int rbase = (lane >> 4) * 4;
    #pragma unroll
    for (int r = 0; r < 4; ++r) {
        const int m = tile0 * 16 + rbase + r;
        if (m < TOUT) atomicAdd(&ob[f * TOUT + m], acc0[r]);
    }
    if (tile1 < 7) {
        #pragma unroll
        for (int r = 0; r < 4; ++r) {
            const int m = tile1 * 16 + rbase + r;
            if (m < TOUT) atomicAdd(&ob[f * TOUT + m], acc1[r]);
        }
    }
}

extern "C" void kernel_launch(void* const* d_in, const int* in_sizes, int n_in,
                              void* d_out, int out_size, void* d_ws, size_t ws_size,
                              hipStream_t stream) {
    const float* x = (const float*)d_in[0];
    const float* w = (const float*)d_in[1];
    const float* g = (const float*)d_in[2];

    hipMemsetAsync(d_out, 0, (size_t)out_size * sizeof(float), stream);
    tgcnn_mfma<<<BB * NCO, 256, 0, stream>>>(x, w, g, (float*)d_out);
}

// Round 9
// 92.858 us; speedup vs baseline: 1.5603x; 1.5603x over previous
//
#include <hip/hip_runtime.h>

// out[b,f,t] = sum_{c,dt} exp(-g*x[b,c,t+dt])[x!=0] * w[c*48+dt*16+f]
// im2col GEMM, M=t (98/batch), N=f (16), K=(c,dt). MFMA bf16 16x16x32.
// Structure = round-5 kernel (best: 86.5us) + replicated ws accumulators
// (rep = bid % nrep) to break the 157-way atomic contention chains.
#define BB     64
#define NNCH   10000
#define TT     100
#define TOUT   98
#define FF     16
#define CPB    64                 // channels per block
#define NCHUNK 157                // ceil(10000/64)
#define EP     116                // E row pitch (ushort): t 0..113 used
#define WP     200                // W row pitch (ushort)
#define ACCN   (TOUT * FF)        // 1568
#define MAXREP 16

typedef __attribute__((ext_vector_type(8))) short s8v;   // 8 bf16
typedef __attribute__((ext_vector_type(4))) float f4v;   // 4 fp32 acc

__device__ __forceinline__ ushort bf_rne(float v) {
    unsigned b = __float_as_uint(v);
    return (ushort)((b + 0x7FFFu + ((b >> 16) & 1u)) >> 16);
}

__global__ __launch_bounds__(256) void tgcnn_mfma(
    const float* __restrict__ x,      // (B, NN, T) fp32
    const float* __restrict__ w,      // (NN*3, 16) fp32: c*48 + dt*16 + f
    const float* __restrict__ gammat, // fp32 scalar
    float* __restrict__ ws,           // nrep x (B, TOUT, F) fp32, pre-zeroed
    int nrep)
{
    __shared__ __align__(16) ushort E[CPB][EP];   // E[c][t] bf16, 14848 B
    __shared__ __align__(16) ushort W[FF][WP];    // W[f][dt*64+c], 6400 B

    const int tid = threadIdx.x;
    const int bid = blockIdx.x;
    const int b   = bid / NCHUNK;
    const int cs  = bid - b * NCHUNK;
    const int cbase = cs * CPB;

    const float gt    = gammat[0];
    const float gamma = 10.0f / (1.0f + __expf(-gt));
    const float kk    = -gamma * 1.4426950408889634f;   // exp(-g*x)=exp2(kk*x)

    // zero LDS (t-pad cols 100..115 and tail-chunk rows must be 0)
    {
        const uint4 z = make_uint4(0, 0, 0, 0);
        uint4* e4 = (uint4*)&E[0][0];
        for (int i = tid; i < (CPB * EP * 2) / 16; i += 256) e4[i] = z;
        uint4* w4 = (uint4*)&W[0][0];
        for (int i = tid; i < (FF * WP * 2) / 16; i += 256) w4[i] = z;
    }
    __syncthreads();

    // Stage E: coalesced float4 loads (4 t of one c), exp, uint2 LDS writes
    const float4* x4 = (const float4*)x;
    for (int i = tid; i < CPB * 25; i += 256) {
        const int cl = i / 25, q = i - cl * 25;
        const int c  = cbase + cl;
        if (c < NNCH) {
            float4 v = x4[((size_t)b * NNCH + c) * 25 + q];
            uint2 p;
            ushort e0 = (v.x != 0.f) ? bf_rne(exp2f(kk * v.x)) : 0;
            ushort e1 = (v.y != 0.f) ? bf_rne(exp2f(kk * v.y)) : 0;
            ushort e2 = (v.z != 0.f) ? bf_rne(exp2f(kk * v.z)) : 0;
            ushort e3 = (v.w != 0.f) ? bf_rne(exp2f(kk * v.w)) : 0;
            p.x = (unsigned)e0 | ((unsigned)e1 << 16);
            p.y = (unsigned)e2 | ((unsigned)e3 << 16);
            *(uint2*)&E[cl][q * 4] = p;
        }
    }

    // Stage W: w[c*48+dt*16+f] -> W[f][dt*64+cl]
    const float4* wg4 = (const float4*)w;
    for (int i = tid; i < CPB * 12; i += 256) {
        const int cl = i / 12, r = i - cl * 12;
        const int dt = r >> 2, fq = (r & 3) * 4;
        const int c  = cbase + cl;
        if (c < NNCH) {
            float4 wv = wg4[(size_t)c * 12 + r];
            const int kp = dt * CPB + cl;
            W[fq + 0][kp] = bf_rne(wv.x);
            W[fq + 1][kp] = bf_rne(wv.y);
            W[fq + 2][kp] = bf_rne(wv.z);
            W[fq + 3][kp] = bf_rne(wv.w);
        }
    }
    __syncthreads();

    // MFMA: 7 t-tiles (M=112, t>=98 masked); wave owns tiles {wave, wave+4}
    const int wave = tid >> 6, lane = tid & 63;
    const int tcol = lane & 15;        // A row (t in tile) / B,D col (f)
    const int kb   = lane >> 4;        // k-octet
    const int tile0 = wave, tile1 = wave + 4;

    f4v acc0 = {0.f, 0.f, 0.f, 0.f};
    f4v acc1 = {0.f, 0.f, 0.f, 0.f};

    #pragma unroll
    for (int ks = 0; ks < 6; ++ks) {
        const int dt = ks >> 1;
        const int cb = (ks & 1) * 32 + kb * 8;

        s8v bfrag = *(const s8v*)&W[tcol][ks * 32 + kb * 8];

        {
            const int trow = tile0 * 16 + tcol + dt;
            s8v afrag;
            #pragma unroll
            for (int j = 0; j < 8; ++j) afrag[j] = (short)E[cb + j][trow];
            acc0 = __builtin_amdgcn_mfma_f32_16x16x32_bf16(afrag, bfrag, acc0, 0, 0, 0);
        }
        if (tile1 < 7) {
            const int trow = tile1 * 16 + tcol + dt;
            s8v afrag;
            #pragma unroll
            for (int j = 0; j < 8; ++j) afrag[j] = (short)E[cb + j][trow];
            acc1 = __builtin_amdgcn_mfma_f32_16x16x32_bf16(afrag, bfrag, acc1, 0, 0, 0);
        }
    }

    // epilogue: atomics into this block's replica (contention / nrep)
    const int rep = bid % nrep;
    float* wsb = ws + ((size_t)rep * BB + b) * ACCN;
    const int f = lane & 15;
    const int rbase = (lane >> 4) * 4;
    #pragma unroll
    for (int r = 0; r < 4; ++r) {
        const int m = tile0 * 16 + rbase + r;
        if (m < TOUT) atomicAdd(&wsb[m * FF + f], acc0[r]);
    }
    if (tile1 < 7) {
        #pragma unroll
        for (int r = 0; r < 4; ++r) {
            const int m = tile1 * 16 + rbase + r;
            if (m < TOUT) atomicAdd(&wsb[m * FF + f], acc1[r]);
        }
    }
}

__global__ __launch_bounds__(256) void tgcnn_finalize(
    const float* __restrict__ ws, float* __restrict__ out, int nrep)
{
    int i = blockIdx.x * 256 + threadIdx.x;
    if (i >= BB * FF * TOUT) return;
    int t = i % TOUT;
    int f = (i / TOUT) & (FF - 1);
    int b = i / (FF * TOUT);
    float s = 0.f;
    for (int r = 0; r < nrep; ++r)
        s += ws[((size_t)r * BB + b) * ACCN + t * FF + f];
    out[i] = s;                        // (B,T,F) -> (B,F,1,T)
}

extern "C" void kernel_launch(void* const* d_in, const int* in_sizes, int n_in,
                              void* d_out, int out_size, void* d_ws, size_t ws_size,
                              hipStream_t stream) {
    const float* x = (const float*)d_in[0];
    const float* w = (const float*)d_in[1];
    const float* g = (const float*)d_in[2];
    float* ws = (float*)d_ws;

    int nrep = (int)(ws_size / ((size_t)BB * ACCN * sizeof(float)));
    if (nrep > MAXREP) nrep = MAXREP;
    if (nrep < 1) nrep = 1;

    hipMemsetAsync(d_ws, 0, (size_t)nrep * BB * ACCN * sizeof(float), stream);
    tgcnn_mfma<<<BB * NCHUNK, 256, 0, stream>>>(x, w, g, ws, nrep);
    tgcnn_finalize<<<(BB * FF * TOUT + 255) / 256, 256, 0, stream>>>(
        ws, (float*)d_out, nrep);
}